// Round 1
// baseline (393.435 us; speedup 1.0000x reference)
//
#include <hip/hip_runtime.h>
#include <hip/hip_bf16.h>

#define NB   32          // sentences
#define SEQ  512
#define HID  768
#define FFN  3072
#define NEXP 8

typedef float f32x4 __attribute__((ext_vector_type(4)));
typedef short s16x8 __attribute__((ext_vector_type(8)));

__device__ __forceinline__ unsigned short f2bf(float f) {
    return __builtin_bit_cast(unsigned short, (__bf16)f);
}

// ---------------------------------------------------------------------------
// Kernel 1: G[b, l, f] = gelu( X[b, l, :] @ W1[e_b][:, f] + b1[e_b][f] )  (bf16 out)
// 128x128 tile, BK=32, 4 waves (2x2 of 64x64), mfma 16x16x32 bf16.
// ---------------------------------------------------------------------------
__global__ __launch_bounds__(256) void moe_ffn1(
    const float* __restrict__ X,      // [NB, SEQ, HID]
    const int*   __restrict__ labels, // [NB]
    const float* __restrict__ W1,     // [E, HID, FFN]
    const float* __restrict__ B1,     // [E, FFN]
    unsigned short* __restrict__ G)   // [NB, SEQ, FFN] bf16
{
    const int nt = blockIdx.x;   // 0..23  (FFN/128)
    const int mt = blockIdx.y;   // 0..3   (SEQ/128)
    const int bs = blockIdx.z;   // 0..31
    const int e  = labels[bs];

    const float* Ag  = X  + ((size_t)bs * SEQ + (size_t)mt * 128) * HID;
    const float* Bg  = W1 + (size_t)e * HID * FFN + (size_t)nt * 128;
    const float* b1g = B1 + (size_t)e * FFN + (size_t)nt * 128;
    unsigned short* Cg = G + ((size_t)bs * SEQ + (size_t)mt * 128) * FFN + (size_t)nt * 128;

    // padded rows: 40 bf16 = 80B (16B-aligned, ~2-way bank conflict = free)
    __shared__ unsigned short As[128 * 40];   // As[m][k]
    __shared__ unsigned short Bs[128 * 40];   // Bs[n][k]  (B stored transposed)

    const int t    = threadIdx.x;
    const int lane = t & 63;
    const int w    = t >> 6;
    const int wm   = (w >> 1) * 64;
    const int wn   = (w & 1) * 64;
    const int fr   = lane & 15;     // fragment row/col index
    const int fq   = lane >> 4;     // k-group / row-group

    f32x4 acc[4][4];
#pragma unroll
    for (int i = 0; i < 4; i++)
#pragma unroll
        for (int j = 0; j < 4; j++) acc[i][j] = (f32x4)0.0f;

    // staging geometry
    const int mA = t >> 1;            // 0..127
    const int kA = (t & 1) * 16;      // 0 / 16
    const int nB = t & 127;           // 0..127
    const int kB = (t >> 7) * 16;     // 0 / 16

    float a_reg[16];
    float b_reg[16];

    auto load_tile = [&](int k0) {
        const float* ap = Ag + (size_t)mA * HID + k0 + kA;
#pragma unroll
        for (int v = 0; v < 4; v++)
            *(f32x4*)&a_reg[v * 4] = *(const f32x4*)(ap + v * 4);
        const float* bp = Bg + (size_t)(k0 + kB) * FFN + nB;
#pragma unroll
        for (int v = 0; v < 16; v++) b_reg[v] = bp[(size_t)v * FFN];
    };

    load_tile(0);

    const int KT = HID / 32;   // 24
    for (int kt = 0; kt < KT; ++kt) {
        __syncthreads();
        {
            unsigned short ta[16], tb[16];
#pragma unroll
            for (int v = 0; v < 16; v++) ta[v] = f2bf(a_reg[v]);
#pragma unroll
            for (int v = 0; v < 16; v++) tb[v] = f2bf(b_reg[v]);
            *(s16x8*)&As[mA * 40 + kA]     = *(s16x8*)&ta[0];
            *(s16x8*)&As[mA * 40 + kA + 8] = *(s16x8*)&ta[8];
            *(s16x8*)&Bs[nB * 40 + kB]     = *(s16x8*)&tb[0];
            *(s16x8*)&Bs[nB * 40 + kB + 8] = *(s16x8*)&tb[8];
        }
        __syncthreads();
        if (kt + 1 < KT) load_tile((kt + 1) * 32);

        s16x8 af[4], bfv[4];
#pragma unroll
        for (int i = 0; i < 4; i++)
            af[i] = *(s16x8*)&As[(wm + i * 16 + fr) * 40 + fq * 8];
#pragma unroll
        for (int j = 0; j < 4; j++)
            bfv[j] = *(s16x8*)&Bs[(wn + j * 16 + fr) * 40 + fq * 8];
#pragma unroll
        for (int i = 0; i < 4; i++)
#pragma unroll
            for (int j = 0; j < 4; j++)
                acc[i][j] = __builtin_amdgcn_mfma_f32_16x16x32_bf16(af[i], bfv[j], acc[i][j], 0, 0, 0);
    }

    // epilogue: bias + exact gelu, store bf16
#pragma unroll
    for (int i = 0; i < 4; i++) {
#pragma unroll
        for (int j = 0; j < 4; j++) {
            const int col = wn + j * 16 + fr;
            const float bias = b1g[col];
#pragma unroll
            for (int r = 0; r < 4; r++) {
                const int row = wm + i * 16 + fq * 4 + r;
                float v = acc[i][j][r] + bias;
                float g = 0.5f * v * (1.0f + erff(v * 0.70710678118654752f));
                Cg[(size_t)row * FFN + col] = f2bf(g);
            }
        }
    }
}

// ---------------------------------------------------------------------------
// Kernel 2: Out[b, l, h] = G[b, l, :] @ W2[e_b][:, h] + b2[e_b][h]   (fp32 out)
// Same structure; A is already bf16 in ws.
// ---------------------------------------------------------------------------
__global__ __launch_bounds__(256) void moe_ffn2(
    const unsigned short* __restrict__ G,  // [NB, SEQ, FFN] bf16
    const int*   __restrict__ labels,
    const float* __restrict__ W2,          // [E, FFN, HID]
    const float* __restrict__ B2,          // [E, HID]
    float* __restrict__ Out)               // [NB, SEQ, HID]
{
    const int nt = blockIdx.x;   // 0..5  (HID/128)
    const int mt = blockIdx.y;   // 0..3
    const int bs = blockIdx.z;   // 0..31
    const int e  = labels[bs];

    const unsigned short* Ag = G + ((size_t)bs * SEQ + (size_t)mt * 128) * FFN;
    const float* Bg  = W2 + (size_t)e * FFN * HID + (size_t)nt * 128;
    const float* b2g = B2 + (size_t)e * HID + (size_t)nt * 128;
    float* Cg = Out + ((size_t)bs * SEQ + (size_t)mt * 128) * HID + (size_t)nt * 128;

    __shared__ unsigned short As[128 * 40];
    __shared__ unsigned short Bs[128 * 40];

    const int t    = threadIdx.x;
    const int lane = t & 63;
    const int w    = t >> 6;
    const int wm   = (w >> 1) * 64;
    const int wn   = (w & 1) * 64;
    const int fr   = lane & 15;
    const int fq   = lane >> 4;

    f32x4 acc[4][4];
#pragma unroll
    for (int i = 0; i < 4; i++)
#pragma unroll
        for (int j = 0; j < 4; j++) acc[i][j] = (f32x4)0.0f;

    const int mA = t >> 1;
    const int kA = (t & 1) * 16;
    const int nB = t & 127;
    const int kB = (t >> 7) * 16;

    s16x8 a_reg[2];
    float b_reg[16];

    auto load_tile = [&](int k0) {
        const unsigned short* ap = Ag + (size_t)mA * FFN + k0 + kA;
        a_reg[0] = *(const s16x8*)(ap);
        a_reg[1] = *(const s16x8*)(ap + 8);
        const float* bp = Bg + (size_t)(k0 + kB) * HID + nB;
#pragma unroll
        for (int v = 0; v < 16; v++) b_reg[v] = bp[(size_t)v * HID];
    };

    load_tile(0);

    const int KT = FFN / 32;   // 96
    for (int kt = 0; kt < KT; ++kt) {
        __syncthreads();
        {
            unsigned short tb[16];
#pragma unroll
            for (int v = 0; v < 16; v++) tb[v] = f2bf(b_reg[v]);
            *(s16x8*)&As[mA * 40 + kA]     = a_reg[0];
            *(s16x8*)&As[mA * 40 + kA + 8] = a_reg[1];
            *(s16x8*)&Bs[nB * 40 + kB]     = *(s16x8*)&tb[0];
            *(s16x8*)&Bs[nB * 40 + kB + 8] = *(s16x8*)&tb[8];
        }
        __syncthreads();
        if (kt + 1 < KT) load_tile((kt + 1) * 32);

        s16x8 af[4], bfv[4];
#pragma unroll
        for (int i = 0; i < 4; i++)
            af[i] = *(s16x8*)&As[(wm + i * 16 + fr) * 40 + fq * 8];
#pragma unroll
        for (int j = 0; j < 4; j++)
            bfv[j] = *(s16x8*)&Bs[(wn + j * 16 + fr) * 40 + fq * 8];
#pragma unroll
        for (int i = 0; i < 4; i++)
#pragma unroll
            for (int j = 0; j < 4; j++)
                acc[i][j] = __builtin_amdgcn_mfma_f32_16x16x32_bf16(af[i], bfv[j], acc[i][j], 0, 0, 0);
    }

#pragma unroll
    for (int i = 0; i < 4; i++) {
#pragma unroll
        for (int j = 0; j < 4; j++) {
            const int col = wn + j * 16 + fr;
            const float bias = b2g[col];
#pragma unroll
            for (int r = 0; r < 4; r++) {
                const int row = wm + i * 16 + fq * 4 + r;
                Cg[(size_t)row * HID + col] = acc[i][j][r] + bias;
            }
        }
    }
}

extern "C" void kernel_launch(void* const* d_in, const int* in_sizes, int n_in,
                              void* d_out, int out_size, void* d_ws, size_t ws_size,
                              hipStream_t stream) {
    const float* X      = (const float*)d_in[0];
    const int*   labels = (const int*)  d_in[1];
    const float* W1     = (const float*)d_in[2];
    const float* B1     = (const float*)d_in[3];
    const float* W2     = (const float*)d_in[4];
    const float* B2     = (const float*)d_in[5];
    float* Out = (float*)d_out;
    unsigned short* G = (unsigned short*)d_ws;   // [NB,SEQ,FFN] bf16 = 100.7 MB

    dim3 g1(FFN / 128, SEQ / 128, NB);   // (24, 4, 32)
    moe_ffn1<<<g1, dim3(256), 0, stream>>>(X, labels, W1, B1, G);

    dim3 g2(HID / 128, SEQ / 128, NB);   // (6, 4, 32)
    moe_ffn2<<<g2, dim3(256), 0, stream>>>(G, labels, W2, B2, Out);
}

// Round 2
// 355.344 us; speedup vs baseline: 1.1072x; 1.1072x over previous
//
#include <hip/hip_runtime.h>
#include <hip/hip_bf16.h>

#define NB   32
#define SEQ  512
#define HID  768
#define FFN  3072
#define NEXP 8

typedef float f32x4 __attribute__((ext_vector_type(4)));
typedef short s16x8 __attribute__((ext_vector_type(8)));

__device__ __forceinline__ unsigned short f2bf(float f) {
    return __builtin_bit_cast(unsigned short, (__bf16)f);
}

// async global->LDS, 16B per lane. LDS dest must be linear lane-ordered.
#define GLOAD16(gp, lp) __builtin_amdgcn_global_load_lds( \
    (const __attribute__((address_space(1))) unsigned int*)(gp), \
    (__attribute__((address_space(3))) unsigned int*)(lp), 16, 0, 0)

// ---------------------------------------------------------------------------
// convert X fp32 -> bf16 (elementwise, vectorized)
// ---------------------------------------------------------------------------
__global__ __launch_bounds__(256) void cvt_x_kernel(
    const float* __restrict__ X, unsigned short* __restrict__ Xb, int n8)
{
    int idx = blockIdx.x * blockDim.x + threadIdx.x;
    int stride = gridDim.x * blockDim.x;
    for (int i = idx; i < n8; i += stride) {
        f32x4 a = *(const f32x4*)(X + (size_t)i * 8);
        f32x4 b = *(const f32x4*)(X + (size_t)i * 8 + 4);
        unsigned short o[8];
#pragma unroll
        for (int v = 0; v < 4; v++) o[v] = f2bf(a[v]);
#pragma unroll
        for (int v = 0; v < 4; v++) o[4 + v] = f2bf(b[v]);
        *(s16x8*)(Xb + (size_t)i * 8) = *(s16x8*)o;
    }
}

// ---------------------------------------------------------------------------
// convert + transpose: in [R][C] fp32 -> out [C][R] bf16, per blockIdx.z slab
// ---------------------------------------------------------------------------
__global__ __launch_bounds__(256) void cvt_transpose_kernel(
    const float* __restrict__ W, unsigned short* __restrict__ WT, int R, int C)
{
    __shared__ unsigned short tile[64][65];
    const int cb = blockIdx.x * 64, rb = blockIdx.y * 64;
    const float* src = W + (size_t)blockIdx.z * R * C;
    unsigned short* dst = WT + (size_t)blockIdx.z * R * C;
    const int x = threadIdx.x & 63, y0 = threadIdx.x >> 6;
#pragma unroll
    for (int i = 0; i < 16; i++) {
        int r = y0 + i * 4;
        tile[r][x] = f2bf(src[(size_t)(rb + r) * C + cb + x]);
    }
    __syncthreads();
#pragma unroll
    for (int i = 0; i < 16; i++) {
        int c = y0 + i * 4;
        dst[(size_t)(cb + c) * R + rb + x] = tile[x][c];
    }
}

// ---------------------------------------------------------------------------
// Staging: one 128x64-elem bf16 tile (16 KB) via 4x global_load_lds_dwordx4.
// LDS linear; global source col-bytes pre-XOR-swizzled so that the LDS image
// is  LDS[row][cb] = A[row][cb ^ ((row&7)<<4)]  (byte addressing within row).
// ---------------------------------------------------------------------------
template<int LDBYTES>
__device__ __forceinline__ void stage_tile(const char* gbase, unsigned short* lds, int t)
{
#pragma unroll
    for (int p = 0; p < 4; p++) {
        int L   = p * 4096 + t * 16;
        int row = L >> 7;
        int cbs = (L & 127) ^ ((row & 7) << 4);
        GLOAD16(gbase + (size_t)row * LDBYTES + cbs, (char*)lds + L);
    }
}

// swizzled fragment read: 8 bf16 at (row, col-byte cbw)
__device__ __forceinline__ s16x8 frag_read(const unsigned short* lds, int row, int cbw)
{
    return *(const s16x8*)((const char*)lds + row * 128 + (cbw ^ ((row & 7) << 4)));
}

// ---------------------------------------------------------------------------
// Kernel 1: G = gelu(Xb @ W1[e] + b1[e])  -> bf16
// A: Xb [m][k] k=HID.  B^T: W1T[e] [n=F][k=H].  128x128 tile, BK=64, 4 waves.
// ---------------------------------------------------------------------------
__global__ __launch_bounds__(256) void moe_gemm1(
    const unsigned short* __restrict__ Xb,
    const int*   __restrict__ labels,
    const unsigned short* __restrict__ W1T,  // [E][FFN][HID] bf16
    const float* __restrict__ B1,            // [E][FFN]
    unsigned short* __restrict__ G)          // [NB][SEQ][FFN] bf16
{
    __shared__ unsigned short As[2][128 * 64];
    __shared__ unsigned short Bs[2][128 * 64];

    const int nt = blockIdx.x, mt = blockIdx.y, bs = blockIdx.z;
    const int e  = labels[bs];

    const char* Ag = (const char*)(Xb + ((size_t)bs * SEQ + (size_t)mt * 128) * HID);
    const char* Bg = (const char*)(W1T + (size_t)e * FFN * HID + (size_t)nt * 128 * HID);
    const float* b1g = B1 + (size_t)e * FFN + (size_t)nt * 128;
    unsigned short* Cg = G + ((size_t)bs * SEQ + (size_t)mt * 128) * FFN + (size_t)nt * 128;

    const int t    = threadIdx.x;
    const int lane = t & 63, w = t >> 6;
    const int wm   = (w >> 1) * 64, wn = (w & 1) * 64;
    const int fr   = lane & 15, fq = lane >> 4;

    f32x4 acc[4][4];
#pragma unroll
    for (int i = 0; i < 4; i++)
#pragma unroll
        for (int j = 0; j < 4; j++) acc[i][j] = (f32x4)0.0f;

    stage_tile<HID * 2>(Ag, As[0], t);
    stage_tile<HID * 2>(Bg, Bs[0], t);
    __syncthreads();

    const int KT = HID / 64;   // 12
    int cur = 0;
    for (int kt = 0; kt < KT; ++kt) {
        if (kt + 1 < KT) {
            stage_tile<HID * 2>(Ag + (size_t)(kt + 1) * 128, As[cur ^ 1], t);
            stage_tile<HID * 2>(Bg + (size_t)(kt + 1) * 128, Bs[cur ^ 1], t);
        }
#pragma unroll
        for (int kk = 0; kk < 2; kk++) {
            s16x8 af[4], bv[4];
#pragma unroll
            for (int i = 0; i < 4; i++)
                af[i] = frag_read(As[cur], wm + i * 16 + fr, kk * 64 + fq * 16);
#pragma unroll
            for (int j = 0; j < 4; j++)
                bv[j] = frag_read(Bs[cur], wn + j * 16 + fr, kk * 64 + fq * 16);
#pragma unroll
            for (int i = 0; i < 4; i++)
#pragma unroll
                for (int j = 0; j < 4; j++)
                    acc[i][j] = __builtin_amdgcn_mfma_f32_16x16x32_bf16(af[i], bv[j], acc[i][j], 0, 0, 0);
        }
        __syncthreads();
        cur ^= 1;
    }

#pragma unroll
    for (int i = 0; i < 4; i++) {
#pragma unroll
        for (int j = 0; j < 4; j++) {
            const int col = wn + j * 16 + fr;
            const float bias = b1g[col];
#pragma unroll
            for (int r = 0; r < 4; r++) {
                const int row = wm + i * 16 + fq * 4 + r;
                float v = acc[i][j][r] + bias;
                float g = 0.5f * v * (1.0f + erff(v * 0.70710678118654752f));
                Cg[(size_t)row * FFN + col] = f2bf(g);
            }
        }
    }
}

// ---------------------------------------------------------------------------
// Kernel 2: Out = G @ W2[e] + b2[e]  -> fp32
// A: G [m][k] k=FFN.  B^T: W2T[e] [n=H][k=F].
// ---------------------------------------------------------------------------
__global__ __launch_bounds__(256) void moe_gemm2(
    const unsigned short* __restrict__ G,
    const int*   __restrict__ labels,
    const unsigned short* __restrict__ W2T,  // [E][HID][FFN] bf16
    const float* __restrict__ B2,            // [E][HID]
    float* __restrict__ Out)                 // [NB][SEQ][HID]
{
    __shared__ unsigned short As[2][128 * 64];
    __shared__ unsigned short Bs[2][128 * 64];

    const int nt = blockIdx.x, mt = blockIdx.y, bs = blockIdx.z;
    const int e  = labels[bs];

    const char* Ag = (const char*)(G + ((size_t)bs * SEQ + (size_t)mt * 128) * FFN);
    const char* Bg = (const char*)(W2T + (size_t)e * HID * FFN + (size_t)nt * 128 * FFN);
    const float* b2g = B2 + (size_t)e * HID + (size_t)nt * 128;
    float* Cg = Out + ((size_t)bs * SEQ + (size_t)mt * 128) * HID + (size_t)nt * 128;

    const int t    = threadIdx.x;
    const int lane = t & 63, w = t >> 6;
    const int wm   = (w >> 1) * 64, wn = (w & 1) * 64;
    const int fr   = lane & 15, fq = lane >> 4;

    f32x4 acc[4][4];
#pragma unroll
    for (int i = 0; i < 4; i++)
#pragma unroll
        for (int j = 0; j < 4; j++) acc[i][j] = (f32x4)0.0f;

    stage_tile<FFN * 2>(Ag, As[0], t);
    stage_tile<FFN * 2>(Bg, Bs[0], t);
    __syncthreads();

    const int KT = FFN / 64;   // 48
    int cur = 0;
    for (int kt = 0; kt < KT; ++kt) {
        if (kt + 1 < KT) {
            stage_tile<FFN * 2>(Ag + (size_t)(kt + 1) * 128, As[cur ^ 1], t);
            stage_tile<FFN * 2>(Bg + (size_t)(kt + 1) * 128, Bs[cur ^ 1], t);
        }
#pragma unroll
        for (int kk = 0; kk < 2; kk++) {
            s16x8 af[4], bv[4];
#pragma unroll
            for (int i = 0; i < 4; i++)
                af[i] = frag_read(As[cur], wm + i * 16 + fr, kk * 64 + fq * 16);
#pragma unroll
            for (int j = 0; j < 4; j++)
                bv[j] = frag_read(Bs[cur], wn + j * 16 + fr, kk * 64 + fq * 16);
#pragma unroll
            for (int i = 0; i < 4; i++)
#pragma unroll
                for (int j = 0; j < 4; j++)
                    acc[i][j] = __builtin_amdgcn_mfma_f32_16x16x32_bf16(af[i], bv[j], acc[i][j], 0, 0, 0);
        }
        __syncthreads();
        cur ^= 1;
    }

#pragma unroll
    for (int i = 0; i < 4; i++) {
#pragma unroll
        for (int j = 0; j < 4; j++) {
            const int col = wn + j * 16 + fr;
            const float bias = b2g[col];
#pragma unroll
            for (int r = 0; r < 4; r++) {
                const int row = wm + i * 16 + fq * 4 + r;
                Cg[(size_t)row * HID + col] = acc[i][j][r] + bias;
            }
        }
    }
}

extern "C" void kernel_launch(void* const* d_in, const int* in_sizes, int n_in,
                              void* d_out, int out_size, void* d_ws, size_t ws_size,
                              hipStream_t stream) {
    const float* X      = (const float*)d_in[0];
    const int*   labels = (const int*)  d_in[1];
    const float* W1     = (const float*)d_in[2];
    const float* B1     = (const float*)d_in[3];
    const float* W2     = (const float*)d_in[4];
    const float* B2     = (const float*)d_in[5];
    float* Out = (float*)d_out;

    // workspace layout (bytes):
    //   Xb   [NB][SEQ][HID] bf16      25,165,824
    //   W1T  [E][FFN][HID]  bf16      37,748,736
    //   W2T  [E][HID][FFN]  bf16      37,748,736
    //   G    [NB][SEQ][FFN] bf16     100,663,296   -> total 201,326,592
    char* ws = (char*)d_ws;
    unsigned short* Xb  = (unsigned short*)(ws);
    unsigned short* W1T = (unsigned short*)(ws + 25165824);
    unsigned short* W2T = (unsigned short*)(ws + 62914560);
    unsigned short* G   = (unsigned short*)(ws + 100663296);

    // converts
    cvt_x_kernel<<<2048, 256, 0, stream>>>(X, Xb, NB * SEQ * HID / 8);
    cvt_transpose_kernel<<<dim3(FFN / 64, HID / 64, NEXP), 256, 0, stream>>>(W1, W1T, HID, FFN);
    cvt_transpose_kernel<<<dim3(HID / 64, FFN / 64, NEXP), 256, 0, stream>>>(W2, W2T, FFN, HID);

    dim3 g1(FFN / 128, SEQ / 128, NB);   // (24, 4, 32)
    moe_gemm1<<<g1, dim3(256), 0, stream>>>(Xb, labels, W1T, B1, G);

    dim3 g2(HID / 128, SEQ / 128, NB);   // (6, 4, 32)
    moe_gemm2<<<g2, dim3(256), 0, stream>>>(G, labels, W2T, B2, Out);
}

// Round 3
// 275.400 us; speedup vs baseline: 1.4286x; 1.2903x over previous
//
#include <hip/hip_runtime.h>
#include <hip/hip_bf16.h>

#define NB   32
#define SEQ  512
#define HID  768
#define FFN  3072
#define NEXP 8

typedef float f32x4 __attribute__((ext_vector_type(4)));
typedef short s16x8 __attribute__((ext_vector_type(8)));

__device__ __forceinline__ unsigned short f2bf(float f) {
    return __builtin_bit_cast(unsigned short, (__bf16)f);
}

#define GLOAD16(gp, lp) __builtin_amdgcn_global_load_lds( \
    (const __attribute__((address_space(1))) unsigned int*)(gp), \
    (__attribute__((address_space(3))) unsigned int*)(lp), 16, 0, 0)

// ---------------------------------------------------------------------------
// convert X fp32 -> bf16
// ---------------------------------------------------------------------------
__global__ __launch_bounds__(256) void cvt_x_kernel(
    const float* __restrict__ X, unsigned short* __restrict__ Xb, int n8)
{
    int idx = blockIdx.x * blockDim.x + threadIdx.x;
    int stride = gridDim.x * blockDim.x;
    for (int i = idx; i < n8; i += stride) {
        f32x4 a = *(const f32x4*)(X + (size_t)i * 8);
        f32x4 b = *(const f32x4*)(X + (size_t)i * 8 + 4);
        unsigned short o[8];
#pragma unroll
        for (int v = 0; v < 4; v++) o[v] = f2bf(a[v]);
#pragma unroll
        for (int v = 0; v < 4; v++) o[4 + v] = f2bf(b[v]);
        *(s16x8*)(Xb + (size_t)i * 8) = *(s16x8*)o;
    }
}

// ---------------------------------------------------------------------------
// convert + transpose: in [R][C] fp32 -> out [C][R] bf16 per slab
// ---------------------------------------------------------------------------
__global__ __launch_bounds__(256) void cvt_transpose_kernel(
    const float* __restrict__ W, unsigned short* __restrict__ WT, int R, int C)
{
    __shared__ unsigned short tile[64][65];
    const int cb = blockIdx.x * 64, rb = blockIdx.y * 64;
    const float* src = W + (size_t)blockIdx.z * R * C;
    unsigned short* dst = WT + (size_t)blockIdx.z * R * C;
    const int x = threadIdx.x & 63, y0 = threadIdx.x >> 6;
#pragma unroll
    for (int i = 0; i < 16; i++) {
        int r = y0 + i * 4;
        tile[r][x] = f2bf(src[(size_t)(rb + r) * C + cb + x]);
    }
    __syncthreads();
#pragma unroll
    for (int i = 0; i < 16; i++) {
        int c = y0 + i * 4;
        dst[(size_t)(cb + c) * R + rb + x] = tile[x][c];
    }
}

// ---------------------------------------------------------------------------
// 256x256 8-phase GEMM machinery (BK=64, 8 waves, 2 LDS buffers of 64KB)
//
// LDS layout (128 KiB dynamic):
//   A buf b: smem + b*32768        (256 rows x 128 B)
//   B buf b: smem + 65536 + b*32768
// Swizzle (T2): LDS[row][cb] = global[row][cb ^ ((row&7)<<4)]; reads XOR same.
//
// Regions (16 KB each, staged by 2 gload_lds per thread):
//   A half h: rows {h*64..h*64+63} U {128+h*64..}
//   B half h: rows {h*32..+31, 64+h*32..+31, 128+h*32.., 192+h*32..}
//
// Window for K-tile t (phases wp0..wp3), quad = (iHalf, jHalf):
//   wp0 quad(0,0): reads A0,B0; stage A1(t+1)->other buf
//   wp1 quad(0,1): reads A0,B1; stage B1(t+1)->other buf
//   wp2 quad(1,0): reads A1,B0; stage A0(t+2)->cur buf   (A0 retired @wp1)
//   wp3 quad(1,1): reads A1,B1; stage B0(t+2)->cur buf   (B0 retired @wp2)
//        + s_waitcnt vmcnt(4) before closing barrier: guarantees ALL of
//          tile t+1 landed (allows only A0/B0(t+2) outstanding). Never 0
//          in the main loop (T4).
// ---------------------------------------------------------------------------
template<int LDB, bool ISA>
__device__ __forceinline__ void stage_region(const char* g, char* lds, int half, int tid)
{
#pragma unroll
    for (int p = 0; p < 2; p++) {
        int L  = p * 8192 + tid * 16;
        int rr = L >> 7;
        int cb = L & 127;
        int row = ISA ? ((rr & 63) + ((rr >> 6) << 7) + half * 64)
                      : ((rr & 31) + ((rr >> 5) << 6) + half * 32);
        int cbs = cb ^ ((row & 7) << 4);
        GLOAD16(g + (size_t)row * LDB + cbs, lds + (size_t)row * 128 + cb);
    }
}

template<int IH, int JH, int VM, class STG>
__device__ __forceinline__ void gphase(const char* Ab, const char* Bb,
    int arow_b, int brow_b, int k0, f32x4 (&acc)[8][4], STG&& stg)
{
    s16x8 a[2][4], b[2][2];
    const int k1 = k0 ^ 64;
#pragma unroll
    for (int i = 0; i < 4; i++) {
        const char* p = Ab + arow_b + (IH * 64 + i * 16) * 128;
        a[0][i] = *(const s16x8*)(p + k0);
        a[1][i] = *(const s16x8*)(p + k1);
    }
#pragma unroll
    for (int j = 0; j < 2; j++) {
        const char* p = Bb + brow_b + (JH * 32 + j * 16) * 128;
        b[0][j] = *(const s16x8*)(p + k0);
        b[1][j] = *(const s16x8*)(p + k1);
    }
    stg();
    __builtin_amdgcn_s_barrier();
    __builtin_amdgcn_s_setprio(1);
#pragma unroll
    for (int kk = 0; kk < 2; kk++)
#pragma unroll
        for (int i = 0; i < 4; i++)
#pragma unroll
            for (int j = 0; j < 2; j++)
                acc[IH * 4 + i][JH * 2 + j] = __builtin_amdgcn_mfma_f32_16x16x32_bf16(
                    a[kk][i], b[kk][j], acc[IH * 4 + i][JH * 2 + j], 0, 0, 0);
    __builtin_amdgcn_s_setprio(0);
    if constexpr (VM >= 0)
        asm volatile("s_waitcnt vmcnt(%0)" :: "i"(VM) : "memory");
    __builtin_amdgcn_s_barrier();
}

template<int LDB, bool S1, bool S2, int VM>
__device__ __forceinline__ void gwindow(const char* AgK, const char* BgK,
    char* Acur, char* Bcur, char* Anxt, char* Bnxt,
    int arow_b, int brow_b, int k0, int tid, f32x4 (&acc)[8][4])
{
    gphase<0, 0, -1>(Acur, Bcur, arow_b, brow_b, k0, acc,
        [&] { if constexpr (S1) stage_region<LDB, true >(AgK + 128, Anxt, 1, tid); });
    gphase<0, 1, -1>(Acur, Bcur, arow_b, brow_b, k0, acc,
        [&] { if constexpr (S1) stage_region<LDB, false>(BgK + 128, Bnxt, 1, tid); });
    gphase<1, 0, -1>(Acur, Bcur, arow_b, brow_b, k0, acc,
        [&] { if constexpr (S2) stage_region<LDB, true >(AgK + 256, Acur, 0, tid); });
    gphase<1, 1, VM>(Acur, Bcur, arow_b, brow_b, k0, acc,
        [&] { if constexpr (S2) stage_region<LDB, false>(BgK + 256, Bcur, 0, tid); });
}

template<int LDB>
__device__ __forceinline__ void gemm_mainloop(const char* Ag, const char* Bg,
    char* smem, int KT, int tid, int arow_b, int brow_b, int k0, f32x4 (&acc)[8][4])
{
    // prologue: issue order A0(0),B0(0),A1(0),B1(0),A0(1),B0(1)
    stage_region<LDB, true >(Ag,       smem,          0, tid);
    stage_region<LDB, false>(Bg,       smem + 65536,  0, tid);
    stage_region<LDB, true >(Ag,       smem,          1, tid);
    stage_region<LDB, false>(Bg,       smem + 65536,  1, tid);
    stage_region<LDB, true >(Ag + 128, smem + 32768,  0, tid);
    stage_region<LDB, false>(Bg + 128, smem + 98304,  0, tid);
    asm volatile("s_waitcnt vmcnt(4)" ::: "memory");
    __builtin_amdgcn_s_barrier();

    int cur = 0;
    for (int kt = 0; kt < KT - 2; ++kt) {
        char* Acur = smem + (cur << 15);
        char* Anxt = smem + ((cur ^ 1) << 15);
        char* Bcur = smem + 65536 + (cur << 15);
        char* Bnxt = smem + 65536 + ((cur ^ 1) << 15);
        gwindow<LDB, true, true, 4>(Ag + (size_t)kt * 128, Bg + (size_t)kt * 128,
            Acur, Bcur, Anxt, Bnxt, arow_b, brow_b, k0, tid, acc);
        cur ^= 1;
    }
    {   // window KT-2: stage A1/B1(KT-1) only; full drain (tail)
        char* Acur = smem + (cur << 15);
        char* Anxt = smem + ((cur ^ 1) << 15);
        char* Bcur = smem + 65536 + (cur << 15);
        char* Bnxt = smem + 65536 + ((cur ^ 1) << 15);
        gwindow<LDB, true, false, 0>(Ag + (size_t)(KT - 2) * 128, Bg + (size_t)(KT - 2) * 128,
            Acur, Bcur, Anxt, Bnxt, arow_b, brow_b, k0, tid, acc);
        cur ^= 1;
    }
    {   // window KT-1: no stages, no wait
        char* Acur = smem + (cur << 15);
        char* Anxt = smem + ((cur ^ 1) << 15);
        char* Bcur = smem + 65536 + (cur << 15);
        char* Bnxt = smem + 65536 + ((cur ^ 1) << 15);
        gwindow<LDB, false, false, -1>(Ag + (size_t)(KT - 1) * 128, Bg + (size_t)(KT - 1) * 128,
            Acur, Bcur, Anxt, Bnxt, arow_b, brow_b, k0, tid, acc);
    }
}

// ---------------------------------------------------------------------------
// Kernel 1: G = gelu(Xb @ W1[e] + b1[e]) -> bf16.  A=Xb[m][k=HID], B^T=W1T[n][k]
// ---------------------------------------------------------------------------
__global__ __launch_bounds__(512, 2) void moe_gemm1(
    const unsigned short* __restrict__ Xb,
    const int*   __restrict__ labels,
    const unsigned short* __restrict__ W1T,  // [E][FFN][HID]
    const float* __restrict__ B1,
    unsigned short* __restrict__ G)
{
    extern __shared__ char smem[];
    const int nt = blockIdx.x, mt = blockIdx.y, bs = blockIdx.z;
    const int e  = labels[bs];

    const char* Ag = (const char*)(Xb + ((size_t)bs * SEQ + (size_t)mt * 256) * HID);
    const char* Bg = (const char*)(W1T + (size_t)e * FFN * HID + (size_t)nt * 256 * HID);

    const int tid = threadIdx.x;
    const int lane = tid & 63, w = tid >> 6;
    const int wm = (w >> 2) * 128, wn = (w & 3) * 64;
    const int fr = lane & 15, fq = lane >> 4;
    const int arow_b = (wm + fr) * 128, brow_b = (wn + fr) * 128;
    const int k0 = (fq * 16) ^ ((fr & 7) << 4);

    f32x4 acc[8][4];
#pragma unroll
    for (int i = 0; i < 8; i++)
#pragma unroll
        for (int j = 0; j < 4; j++) acc[i][j] = (f32x4)0.0f;

    gemm_mainloop<HID * 2>(Ag, Bg, smem, HID / 64, tid, arow_b, brow_b, k0, acc);

    const float* b1g = B1 + (size_t)e * FFN + (size_t)nt * 256;
    unsigned short* Cg = G + ((size_t)bs * SEQ + (size_t)mt * 256) * FFN + (size_t)nt * 256;
#pragma unroll
    for (int mi = 0; mi < 8; mi++)
#pragma unroll
        for (int nj = 0; nj < 4; nj++) {
            const int col = wn + nj * 16 + fr;
            const float bias = b1g[col];
#pragma unroll
            for (int r = 0; r < 4; r++) {
                const int row = wm + mi * 16 + fq * 4 + r;
                float v = acc[mi][nj][r] + bias;
                float g = 0.5f * v * (1.0f + erff(v * 0.70710678118654752f));
                Cg[(size_t)row * FFN + col] = f2bf(g);
            }
        }
}

// ---------------------------------------------------------------------------
// Kernel 2: Out = G @ W2[e] + b2[e] -> fp32.  A=G[m][k=FFN], B^T=W2T[n][k]
// ---------------------------------------------------------------------------
__global__ __launch_bounds__(512, 2) void moe_gemm2(
    const unsigned short* __restrict__ G,
    const int*   __restrict__ labels,
    const unsigned short* __restrict__ W2T,  // [E][HID][FFN]
    const float* __restrict__ B2,
    float* __restrict__ Out)
{
    extern __shared__ char smem[];
    const int nt = blockIdx.x, mt = blockIdx.y, bs = blockIdx.z;
    const int e  = labels[bs];

    const char* Ag = (const char*)(G + ((size_t)bs * SEQ + (size_t)mt * 256) * FFN);
    const char* Bg = (const char*)(W2T + (size_t)e * HID * FFN + (size_t)nt * 256 * FFN);

    const int tid = threadIdx.x;
    const int lane = tid & 63, w = tid >> 6;
    const int wm = (w >> 2) * 128, wn = (w & 3) * 64;
    const int fr = lane & 15, fq = lane >> 4;
    const int arow_b = (wm + fr) * 128, brow_b = (wn + fr) * 128;
    const int k0 = (fq * 16) ^ ((fr & 7) << 4);

    f32x4 acc[8][4];
#pragma unroll
    for (int i = 0; i < 8; i++)
#pragma unroll
        for (int j = 0; j < 4; j++) acc[i][j] = (f32x4)0.0f;

    gemm_mainloop<FFN * 2>(Ag, Bg, smem, FFN / 64, tid, arow_b, brow_b, k0, acc);

    const float* b2g = B2 + (size_t)e * HID + (size_t)nt * 256;
    float* Cg = Out + ((size_t)bs * SEQ + (size_t)mt * 256) * HID + (size_t)nt * 256;
#pragma unroll
    for (int mi = 0; mi < 8; mi++)
#pragma unroll
        for (int nj = 0; nj < 4; nj++) {
            const int col = wn + nj * 16 + fr;
            const float bias = b2g[col];
#pragma unroll
            for (int r = 0; r < 4; r++) {
                const int row = wm + mi * 16 + fq * 4 + r;
                Cg[(size_t)row * HID + col] = acc[mi][nj][r] + bias;
            }
        }
}

extern "C" void kernel_launch(void* const* d_in, const int* in_sizes, int n_in,
                              void* d_out, int out_size, void* d_ws, size_t ws_size,
                              hipStream_t stream) {
    const float* X      = (const float*)d_in[0];
    const int*   labels = (const int*)  d_in[1];
    const float* W1     = (const float*)d_in[2];
    const float* B1     = (const float*)d_in[3];
    const float* W2     = (const float*)d_in[4];
    const float* B2     = (const float*)d_in[5];
    float* Out = (float*)d_out;

    char* ws = (char*)d_ws;
    unsigned short* Xb  = (unsigned short*)(ws);               // 25,165,824 B
    unsigned short* W1T = (unsigned short*)(ws + 25165824);    // 37,748,736 B
    unsigned short* W2T = (unsigned short*)(ws + 62914560);    // 37,748,736 B
    unsigned short* G   = (unsigned short*)(ws + 100663296);   // 100,663,296 B

    // allow 128 KiB dynamic LDS (idempotent; not a stream op)
    (void)hipFuncSetAttribute((const void*)moe_gemm1,
        hipFuncAttributeMaxDynamicSharedMemorySize, 131072);
    (void)hipFuncSetAttribute((const void*)moe_gemm2,
        hipFuncAttributeMaxDynamicSharedMemorySize, 131072);

    cvt_x_kernel<<<2048, 256, 0, stream>>>(X, Xb, NB * SEQ * HID / 8);
    cvt_transpose_kernel<<<dim3(FFN / 64, HID / 64, NEXP), 256, 0, stream>>>(W1, W1T, HID, FFN);
    cvt_transpose_kernel<<<dim3(HID / 64, FFN / 64, NEXP), 256, 0, stream>>>(W2, W2T, FFN, HID);

    dim3 g1(FFN / 256, SEQ / 256, NB);   // (12, 2, 32) = 768 blocks
    moe_gemm1<<<g1, dim3(512), 131072, stream>>>(Xb, labels, W1T, B1, G);

    dim3 g2(HID / 256, SEQ / 256, NB);   // (3, 2, 32) = 192 blocks
    moe_gemm2<<<g2, dim3(512), 131072, stream>>>(G, labels, W2T, B2, Out);
}

// Round 4
// 239.344 us; speedup vs baseline: 1.6438x; 1.1506x over previous
//
#include <hip/hip_runtime.h>
#include <hip/hip_bf16.h>

#define NB   32
#define SEQ  512
#define HID  768
#define FFN  3072
#define NEXP 8

typedef float f32x4 __attribute__((ext_vector_type(4)));
typedef short s16x8 __attribute__((ext_vector_type(8)));

__device__ __forceinline__ unsigned short f2bf(float f) {
    return __builtin_bit_cast(unsigned short, (__bf16)f);
}

__device__ __forceinline__ float fast_exp2(float x) {
    float r; asm("v_exp_f32 %0, %1" : "=v"(r) : "v"(x)); return r;
}
__device__ __forceinline__ float fast_rcp(float x) {
    float r; asm("v_rcp_f32 %0, %1" : "=v"(r) : "v"(x)); return r;
}

// tanh-gelu, overflow-free (exp2 arg <= 0). |error| vs exact-erf gelu ~2e-4.
__device__ __forceinline__ float gelu_fast(float v) {
    float u  = v * (0.7978845608f + 0.0356774081f * v * v);
    float t  = fast_exp2(-2.8853900817779268f * fabsf(u));   // e^{-2|u|}
    float T  = (1.0f - t) * fast_rcp(1.0f + t);              // tanh(|u|)
    return 0.5f * v + 0.5f * fabsf(v) * T;
}

#define GLOAD16(gp, lp) __builtin_amdgcn_global_load_lds( \
    (const __attribute__((address_space(1))) unsigned int*)(gp), \
    (__attribute__((address_space(3))) unsigned int*)(lp), 16, 0, 0)

// ---------------------------------------------------------------------------
// convert X fp32 -> bf16
// ---------------------------------------------------------------------------
__global__ __launch_bounds__(256) void cvt_x_kernel(
    const float* __restrict__ X, unsigned short* __restrict__ Xb, int n8)
{
    int idx = blockIdx.x * blockDim.x + threadIdx.x;
    int stride = gridDim.x * blockDim.x;
    for (int i = idx; i < n8; i += stride) {
        f32x4 a = *(const f32x4*)(X + (size_t)i * 8);
        f32x4 b = *(const f32x4*)(X + (size_t)i * 8 + 4);
        unsigned short o[8];
#pragma unroll
        for (int v = 0; v < 4; v++) o[v] = f2bf(a[v]);
#pragma unroll
        for (int v = 0; v < 4; v++) o[4 + v] = f2bf(b[v]);
        *(s16x8*)(Xb + (size_t)i * 8) = *(s16x8*)o;
    }
}

// ---------------------------------------------------------------------------
// convert + transpose: in [R][C] fp32 -> out [C][R] bf16 per slab
// ---------------------------------------------------------------------------
__global__ __launch_bounds__(256) void cvt_transpose_kernel(
    const float* __restrict__ W, unsigned short* __restrict__ WT, int R, int C)
{
    __shared__ unsigned short tile[64][65];
    const int cb = blockIdx.x * 64, rb = blockIdx.y * 64;
    const float* src = W + (size_t)blockIdx.z * R * C;
    unsigned short* dst = WT + (size_t)blockIdx.z * R * C;
    const int x = threadIdx.x & 63, y0 = threadIdx.x >> 6;
#pragma unroll
    for (int i = 0; i < 16; i++) {
        int r = y0 + i * 4;
        tile[r][x] = f2bf(src[(size_t)(rb + r) * C + cb + x]);
    }
    __syncthreads();
#pragma unroll
    for (int i = 0; i < 16; i++) {
        int c = y0 + i * 4;
        dst[(size_t)(cb + c) * R + rb + x] = tile[x][c];
    }
}

// ---------------------------------------------------------------------------
// 256x256 8-phase GEMM (BK=64, 8 waves, 2 LDS buffers of 64KB).
// Phase order per window (frag-persistent, 24 ds_read_b128/window/wave):
//   wp0 (A0,B0): read a<-A0 (8), b0<-B0 (4); stage A1(t+1)->nxt
//   wp1 (A0,B1): read b1<-B1 (4);            stage B1(t+1)->nxt
//   wp2 (A1,B1): read a<-A1 (8);             stage A0(t+2)->cur  (A0 last read wp0)
//   wp3 (A1,B0): regs only;                  stage B0(t+2)->cur  (B0 last read wp0)
//        + vmcnt(4): tile t+1 fully landed, A0/B0(t+2) may stay in flight (T4).
// ---------------------------------------------------------------------------
template<int LDB, bool ISA>
__device__ __forceinline__ void stage_region(const char* g, char* lds, int half, int tid)
{
#pragma unroll
    for (int p = 0; p < 2; p++) {
        int L  = p * 8192 + tid * 16;
        int rr = L >> 7;
        int cb = L & 127;
        int row = ISA ? ((rr & 63) + ((rr >> 6) << 7) + half * 64)
                      : ((rr & 31) + ((rr >> 5) << 6) + half * 32);
        int cbs = cb ^ ((row & 7) << 4);
        GLOAD16(g + (size_t)row * LDB + cbs, lds + (size_t)row * 128 + cb);
    }
}

__device__ __forceinline__ void read_af(const char* Ab, int arow_b, int k0, int ih, s16x8 (&a)[2][4])
{
    const int k1 = k0 ^ 64;
#pragma unroll
    for (int i = 0; i < 4; i++) {
        const char* p = Ab + arow_b + (ih * 64 + i * 16) * 128;
        a[0][i] = *(const s16x8*)(p + k0);
        a[1][i] = *(const s16x8*)(p + k1);
    }
}
__device__ __forceinline__ void read_bf(const char* Bb, int brow_b, int k0, int jh, s16x8 (&b)[2][2])
{
    const int k1 = k0 ^ 64;
#pragma unroll
    for (int j = 0; j < 2; j++) {
        const char* p = Bb + brow_b + (jh * 32 + j * 16) * 128;
        b[0][j] = *(const s16x8*)(p + k0);
        b[1][j] = *(const s16x8*)(p + k1);
    }
}

template<int IH, int JH>
__device__ __forceinline__ void mfma_quad(s16x8 (&a)[2][4], s16x8 (&b)[2][2], f32x4 (&acc)[8][4])
{
    __builtin_amdgcn_s_setprio(1);
#pragma unroll
    for (int kk = 0; kk < 2; kk++)
#pragma unroll
        for (int i = 0; i < 4; i++)
#pragma unroll
            for (int j = 0; j < 2; j++)
                acc[IH * 4 + i][JH * 2 + j] = __builtin_amdgcn_mfma_f32_16x16x32_bf16(
                    a[kk][i], b[kk][j], acc[IH * 4 + i][JH * 2 + j], 0, 0, 0);
    __builtin_amdgcn_s_setprio(0);
}

template<int LDB, bool S1, bool S2, int VM>
__device__ __forceinline__ void gwindow(const char* AgK, const char* BgK,
    char* Acur, char* Bcur, char* Anxt, char* Bnxt,
    int arow_b, int brow_b, int k0, int tid, f32x4 (&acc)[8][4])
{
    s16x8 a[2][4], b0[2][2], b1[2][2];
    // wp0 (A0,B0)
    read_af(Acur, arow_b, k0, 0, a);
    read_bf(Bcur, brow_b, k0, 0, b0);
    if constexpr (S1) stage_region<LDB, true >(AgK + 128, Anxt, 1, tid);
    __builtin_amdgcn_s_barrier();
    mfma_quad<0, 0>(a, b0, acc);
    __builtin_amdgcn_s_barrier();
    // wp1 (A0,B1)
    read_bf(Bcur, brow_b, k0, 1, b1);
    if constexpr (S1) stage_region<LDB, false>(BgK + 128, Bnxt, 1, tid);
    __builtin_amdgcn_s_barrier();
    mfma_quad<0, 1>(a, b1, acc);
    __builtin_amdgcn_s_barrier();
    // wp2 (A1,B1)
    read_af(Acur, arow_b, k0, 1, a);
    if constexpr (S2) stage_region<LDB, true >(AgK + 256, Acur, 0, tid);
    __builtin_amdgcn_s_barrier();
    mfma_quad<1, 1>(a, b1, acc);
    __builtin_amdgcn_s_barrier();
    // wp3 (A1,B0) — all operands already in regs
    if constexpr (S2) stage_region<LDB, false>(BgK + 256, Bcur, 0, tid);
    __builtin_amdgcn_s_barrier();
    mfma_quad<1, 0>(a, b0, acc);
    if constexpr (VM >= 0)
        asm volatile("s_waitcnt vmcnt(%0)" :: "i"(VM) : "memory");
    __builtin_amdgcn_s_barrier();
}

template<int LDB>
__device__ __forceinline__ void gemm_mainloop(const char* Ag, const char* Bg,
    char* smem, int KT, int tid, int arow_b, int brow_b, int k0, f32x4 (&acc)[8][4])
{
    // prologue: A0(0),B0(0),A1(0),B1(0),A0(1),B0(1)
    stage_region<LDB, true >(Ag,       smem,          0, tid);
    stage_region<LDB, false>(Bg,       smem + 65536,  0, tid);
    stage_region<LDB, true >(Ag,       smem,          1, tid);
    stage_region<LDB, false>(Bg,       smem + 65536,  1, tid);
    stage_region<LDB, true >(Ag + 128, smem + 32768,  0, tid);
    stage_region<LDB, false>(Bg + 128, smem + 98304,  0, tid);
    asm volatile("s_waitcnt vmcnt(4)" ::: "memory");
    __builtin_amdgcn_s_barrier();

    int cur = 0;
    for (int kt = 0; kt < KT - 2; ++kt) {
        char* Acur = smem + (cur << 15);
        char* Anxt = smem + ((cur ^ 1) << 15);
        char* Bcur = smem + 65536 + (cur << 15);
        char* Bnxt = smem + 65536 + ((cur ^ 1) << 15);
        gwindow<LDB, true, true, 4>(Ag + (size_t)kt * 128, Bg + (size_t)kt * 128,
            Acur, Bcur, Anxt, Bnxt, arow_b, brow_b, k0, tid, acc);
        cur ^= 1;
    }
    {   // window KT-2: stage A1/B1(KT-1) only; drain
        char* Acur = smem + (cur << 15);
        char* Anxt = smem + ((cur ^ 1) << 15);
        char* Bcur = smem + 65536 + (cur << 15);
        char* Bnxt = smem + 65536 + ((cur ^ 1) << 15);
        gwindow<LDB, true, false, 0>(Ag + (size_t)(KT - 2) * 128, Bg + (size_t)(KT - 2) * 128,
            Acur, Bcur, Anxt, Bnxt, arow_b, brow_b, k0, tid, acc);
        cur ^= 1;
    }
    {   // window KT-1: no stages, no wait
        char* Acur = smem + (cur << 15);
        char* Anxt = smem + ((cur ^ 1) << 15);
        char* Bcur = smem + 65536 + (cur << 15);
        char* Bnxt = smem + 65536 + ((cur ^ 1) << 15);
        gwindow<LDB, false, false, -1>(Ag + (size_t)(KT - 1) * 128, Bg + (size_t)(KT - 1) * 128,
            Acur, Bcur, Anxt, Bnxt, arow_b, brow_b, k0, tid, acc);
    }
}

// ---------------------------------------------------------------------------
// Kernel 1: G = gelu(Xb @ W1[e] + b1[e]) -> bf16
// ---------------------------------------------------------------------------
__global__ __launch_bounds__(512, 2) void moe_gemm1(
    const unsigned short* __restrict__ Xb,
    const int*   __restrict__ labels,
    const unsigned short* __restrict__ W1T,  // [E][FFN][HID]
    const float* __restrict__ B1,
    unsigned short* __restrict__ G)
{
    extern __shared__ char smem[];
    const int nt = blockIdx.x, mt = blockIdx.y, bs = blockIdx.z;
    const int e  = labels[bs];

    const char* Ag = (const char*)(Xb + ((size_t)bs * SEQ + (size_t)mt * 256) * HID);
    const char* Bg = (const char*)(W1T + (size_t)e * FFN * HID + (size_t)nt * 256 * HID);

    const int tid = threadIdx.x;
    const int lane = tid & 63, w = tid >> 6;
    const int wm = (w >> 2) * 128, wn = (w & 3) * 64;
    const int fr = lane & 15, fq = lane >> 4;
    const int arow_b = (wm + fr) * 128, brow_b = (wn + fr) * 128;
    const int k0 = (fq * 16) ^ ((fr & 7) << 4);

    f32x4 acc[8][4];
#pragma unroll
    for (int i = 0; i < 8; i++)
#pragma unroll
        for (int j = 0; j < 4; j++) acc[i][j] = (f32x4)0.0f;

    gemm_mainloop<HID * 2>(Ag, Bg, smem, HID / 64, tid, arow_b, brow_b, k0, acc);

    const float* b1g = B1 + (size_t)e * FFN + (size_t)nt * 256;
    unsigned short* Cg = G + ((size_t)bs * SEQ + (size_t)mt * 256) * FFN + (size_t)nt * 256;
    float bias[4];
#pragma unroll
    for (int nj = 0; nj < 4; nj++) bias[nj] = b1g[wn + nj * 16 + fr];
#pragma unroll
    for (int mi = 0; mi < 8; mi++)
#pragma unroll
        for (int nj = 0; nj < 4; nj++) {
            const int col = wn + nj * 16 + fr;
#pragma unroll
            for (int r = 0; r < 4; r++) {
                const int row = wm + mi * 16 + fq * 4 + r;
                float v = acc[mi][nj][r] + bias[nj];
                Cg[(size_t)row * FFN + col] = f2bf(gelu_fast(v));
            }
        }
}

// ---------------------------------------------------------------------------
// Kernel 2: Out = G @ W2[e] + b2[e] -> fp32
// ---------------------------------------------------------------------------
__global__ __launch_bounds__(512, 2) void moe_gemm2(
    const unsigned short* __restrict__ G,
    const int*   __restrict__ labels,
    const unsigned short* __restrict__ W2T,  // [E][HID][FFN]
    const float* __restrict__ B2,
    float* __restrict__ Out)
{
    extern __shared__ char smem[];
    const int nt = blockIdx.x, mt = blockIdx.y, bs = blockIdx.z;
    const int e  = labels[bs];

    const char* Ag = (const char*)(G + ((size_t)bs * SEQ + (size_t)mt * 256) * FFN);
    const char* Bg = (const char*)(W2T + (size_t)e * HID * FFN + (size_t)nt * 256 * FFN);

    const int tid = threadIdx.x;
    const int lane = tid & 63, w = tid >> 6;
    const int wm = (w >> 2) * 128, wn = (w & 3) * 64;
    const int fr = lane & 15, fq = lane >> 4;
    const int arow_b = (wm + fr) * 128, brow_b = (wn + fr) * 128;
    const int k0 = (fq * 16) ^ ((fr & 7) << 4);

    f32x4 acc[8][4];
#pragma unroll
    for (int i = 0; i < 8; i++)
#pragma unroll
        for (int j = 0; j < 4; j++) acc[i][j] = (f32x4)0.0f;

    gemm_mainloop<FFN * 2>(Ag, Bg, smem, FFN / 64, tid, arow_b, brow_b, k0, acc);

    const float* b2g = B2 + (size_t)e * HID + (size_t)nt * 256;
    float* Cg = Out + ((size_t)bs * SEQ + (size_t)mt * 256) * HID + (size_t)nt * 256;
    float bias[4];
#pragma unroll
    for (int nj = 0; nj < 4; nj++) bias[nj] = b2g[wn + nj * 16 + fr];
#pragma unroll
    for (int mi = 0; mi < 8; mi++)
#pragma unroll
        for (int nj = 0; nj < 4; nj++) {
            const int col = wn + nj * 16 + fr;
#pragma unroll
            for (int r = 0; r < 4; r++) {
                const int row = wm + mi * 16 + fq * 4 + r;
                Cg[(size_t)row * HID + col] = acc[mi][nj][r] + bias[nj];
            }
        }
}

extern "C" void kernel_launch(void* const* d_in, const int* in_sizes, int n_in,
                              void* d_out, int out_size, void* d_ws, size_t ws_size,
                              hipStream_t stream) {
    const float* X      = (const float*)d_in[0];
    const int*   labels = (const int*)  d_in[1];
    const float* W1     = (const float*)d_in[2];
    const float* B1     = (const float*)d_in[3];
    const float* W2     = (const float*)d_in[4];
    const float* B2     = (const float*)d_in[5];
    float* Out = (float*)d_out;

    char* ws = (char*)d_ws;
    unsigned short* Xb  = (unsigned short*)(ws);               // 25,165,824 B
    unsigned short* W1T = (unsigned short*)(ws + 25165824);    // 37,748,736 B
    unsigned short* W2T = (unsigned short*)(ws + 62914560);    // 37,748,736 B
    unsigned short* G   = (unsigned short*)(ws + 100663296);   // 100,663,296 B

    (void)hipFuncSetAttribute((const void*)moe_gemm1,
        hipFuncAttributeMaxDynamicSharedMemorySize, 131072);
    (void)hipFuncSetAttribute((const void*)moe_gemm2,
        hipFuncAttributeMaxDynamicSharedMemorySize, 131072);

    cvt_x_kernel<<<2048, 256, 0, stream>>>(X, Xb, NB * SEQ * HID / 8);
    cvt_transpose_kernel<<<dim3(FFN / 64, HID / 64, NEXP), 256, 0, stream>>>(W1, W1T, HID, FFN);
    cvt_transpose_kernel<<<dim3(HID / 64, FFN / 64, NEXP), 256, 0, stream>>>(W2, W2T, FFN, HID);

    dim3 g1(FFN / 256, SEQ / 256, NB);   // (12, 2, 32) = 768 blocks
    moe_gemm1<<<g1, dim3(512), 131072, stream>>>(Xb, labels, W1T, B1, G);

    dim3 g2(HID / 256, SEQ / 256, NB);   // (3, 2, 32) = 192 blocks
    moe_gemm2<<<g2, dim3(512), 131072, stream>>>(G, labels, W2T, B2, Out);
}

// Round 5
// 236.799 us; speedup vs baseline: 1.6615x; 1.0107x over previous
//
#include <hip/hip_runtime.h>
#include <hip/hip_bf16.h>

#define NB   32
#define SEQ  512
#define HID  768
#define FFN  3072
#define NEXP 8

typedef float f32x4 __attribute__((ext_vector_type(4)));
typedef short s16x8 __attribute__((ext_vector_type(8)));

__device__ __forceinline__ unsigned short f2bf(float f) {
    return __builtin_bit_cast(unsigned short, (__bf16)f);
}

__device__ __forceinline__ float fast_exp2(float x) {
    float r; asm("v_exp_f32 %0, %1" : "=v"(r) : "v"(x)); return r;
}
__device__ __forceinline__ float fast_rcp(float x) {
    float r; asm("v_rcp_f32 %0, %1" : "=v"(r) : "v"(x)); return r;
}

// tanh-gelu, overflow-free (exp2 arg <= 0). |error| vs exact-erf gelu ~2e-4.
__device__ __forceinline__ float gelu_fast(float v) {
    float u  = v * (0.7978845608f + 0.0356774081f * v * v);
    float t  = fast_exp2(-2.8853900817779268f * fabsf(u));   // e^{-2|u|}
    float T  = (1.0f - t) * fast_rcp(1.0f + t);              // tanh(|u|)
    return 0.5f * v + 0.5f * fabsf(v) * T;
}

#define GLOAD16(gp, lp) __builtin_amdgcn_global_load_lds( \
    (const __attribute__((address_space(1))) unsigned int*)(gp), \
    (__attribute__((address_space(3))) unsigned int*)(lp), 16, 0, 0)

// ---------------------------------------------------------------------------
// stable counting-sort permutation of sentences by expert label (1 wave)
// perm[rank] = original sentence index; deterministic.
// ---------------------------------------------------------------------------
__global__ void sort_labels_kernel(const int* __restrict__ labels, int* __restrict__ perm)
{
    int i = threadIdx.x;
    if (i < NB) {
        int li = labels[i];
        int rank = 0;
        for (int j = 0; j < NB; j++) {
            int lj = labels[j];
            if (lj < li || (lj == li && j < i)) rank++;
        }
        perm[rank] = i;
    }
}

// ---------------------------------------------------------------------------
// convert X fp32 -> bf16
// ---------------------------------------------------------------------------
__global__ __launch_bounds__(256) void cvt_x_kernel(
    const float* __restrict__ X, unsigned short* __restrict__ Xb, int n8)
{
    int idx = blockIdx.x * blockDim.x + threadIdx.x;
    int stride = gridDim.x * blockDim.x;
    for (int i = idx; i < n8; i += stride) {
        f32x4 a = *(const f32x4*)(X + (size_t)i * 8);
        f32x4 b = *(const f32x4*)(X + (size_t)i * 8 + 4);
        unsigned short o[8];
#pragma unroll
        for (int v = 0; v < 4; v++) o[v] = f2bf(a[v]);
#pragma unroll
        for (int v = 0; v < 4; v++) o[4 + v] = f2bf(b[v]);
        *(s16x8*)(Xb + (size_t)i * 8) = *(s16x8*)o;
    }
}

// ---------------------------------------------------------------------------
// convert + transpose: in [R][C] fp32 -> out [C][R] bf16 per slab
// ---------------------------------------------------------------------------
__global__ __launch_bounds__(256) void cvt_transpose_kernel(
    const float* __restrict__ W, unsigned short* __restrict__ WT, int R, int C)
{
    __shared__ unsigned short tile[64][65];
    const int cb = blockIdx.x * 64, rb = blockIdx.y * 64;
    const float* src = W + (size_t)blockIdx.z * R * C;
    unsigned short* dst = WT + (size_t)blockIdx.z * R * C;
    const int x = threadIdx.x & 63, y0 = threadIdx.x >> 6;
#pragma unroll
    for (int i = 0; i < 16; i++) {
        int r = y0 + i * 4;
        tile[r][x] = f2bf(src[(size_t)(rb + r) * C + cb + x]);
    }
    __syncthreads();
#pragma unroll
    for (int i = 0; i < 16; i++) {
        int c = y0 + i * 4;
        dst[(size_t)(cb + c) * R + rb + x] = tile[x][c];
    }
}

// ---------------------------------------------------------------------------
// 256x256 8-phase GEMM (BK=64, 8 waves, 2 LDS buffers of 64KB).
// Phase order per window (frag-persistent, 24 ds_read_b128/window/wave):
//   wp0 (A0,B0): read a<-A0 (8), b0<-B0 (4); stage A1(t+1)->nxt
//   wp1 (A0,B1): read b1<-B1 (4);            stage B1(t+1)->nxt
//   wp2 (A1,B1): read a<-A1 (8);             stage A0(t+2)->cur
//   wp3 (A1,B0): regs only;                  stage B0(t+2)->cur
//        + vmcnt(4): tile t+1 fully landed (T4, never 0 mid-loop).
// ---------------------------------------------------------------------------
template<int LDB, bool ISA>
__device__ __forceinline__ void stage_region(const char* g, char* lds, int half, int tid)
{
#pragma unroll
    for (int p = 0; p < 2; p++) {
        int L  = p * 8192 + tid * 16;
        int rr = L >> 7;
        int cb = L & 127;
        int row = ISA ? ((rr & 63) + ((rr >> 6) << 7) + half * 64)
                      : ((rr & 31) + ((rr >> 5) << 6) + half * 32);
        int cbs = cb ^ ((row & 7) << 4);
        GLOAD16(g + (size_t)row * LDB + cbs, lds + (size_t)row * 128 + cb);
    }
}

__device__ __forceinline__ void read_af(const char* Ab, int arow_b, int k0, int ih, s16x8 (&a)[2][4])
{
    const int k1 = k0 ^ 64;
#pragma unroll
    for (int i = 0; i < 4; i++) {
        const char* p = Ab + arow_b + (ih * 64 + i * 16) * 128;
        a[0][i] = *(const s16x8*)(p + k0);
        a[1][i] = *(const s16x8*)(p + k1);
    }
}
__device__ __forceinline__ void read_bf(const char* Bb, int brow_b, int k0, int jh, s16x8 (&b)[2][2])
{
    const int k1 = k0 ^ 64;
#pragma unroll
    for (int j = 0; j < 2; j++) {
        const char* p = Bb + brow_b + (jh * 32 + j * 16) * 128;
        b[0][j] = *(const s16x8*)(p + k0);
        b[1][j] = *(const s16x8*)(p + k1);
    }
}

template<int IH, int JH>
__device__ __forceinline__ void mfma_quad(s16x8 (&a)[2][4], s16x8 (&b)[2][2], f32x4 (&acc)[8][4])
{
    __builtin_amdgcn_s_setprio(1);
#pragma unroll
    for (int kk = 0; kk < 2; kk++)
#pragma unroll
        for (int i = 0; i < 4; i++)
#pragma unroll
            for (int j = 0; j < 2; j++)
                acc[IH * 4 + i][JH * 2 + j] = __builtin_amdgcn_mfma_f32_16x16x32_bf16(
                    a[kk][i], b[kk][j], acc[IH * 4 + i][JH * 2 + j], 0, 0, 0);
    __builtin_amdgcn_s_setprio(0);
}

template<int LDB, bool S1, bool S2, int VM>
__device__ __forceinline__ void gwindow(const char* AgK, const char* BgK,
    char* Acur, char* Bcur, char* Anxt, char* Bnxt,
    int arow_b, int brow_b, int k0, int tid, f32x4 (&acc)[8][4])
{
    s16x8 a[2][4], b0[2][2], b1[2][2];
    // wp0 (A0,B0)
    read_af(Acur, arow_b, k0, 0, a);
    read_bf(Bcur, brow_b, k0, 0, b0);
    if constexpr (S1) stage_region<LDB, true >(AgK + 128, Anxt, 1, tid);
    __builtin_amdgcn_s_barrier();
    mfma_quad<0, 0>(a, b0, acc);
    __builtin_amdgcn_s_barrier();
    // wp1 (A0,B1)
    read_bf(Bcur, brow_b, k0, 1, b1);
    if constexpr (S1) stage_region<LDB, false>(BgK + 128, Bnxt, 1, tid);
    __builtin_amdgcn_s_barrier();
    mfma_quad<0, 1>(a, b1, acc);
    __builtin_amdgcn_s_barrier();
    // wp2 (A1,B1)
    read_af(Acur, arow_b, k0, 1, a);
    if constexpr (S2) stage_region<LDB, true >(AgK + 256, Acur, 0, tid);
    __builtin_amdgcn_s_barrier();
    mfma_quad<1, 1>(a, b1, acc);
    __builtin_amdgcn_s_barrier();
    // wp3 (A1,B0) — all operands already in regs
    if constexpr (S2) stage_region<LDB, false>(BgK + 256, Bcur, 0, tid);
    __builtin_amdgcn_s_barrier();
    mfma_quad<1, 0>(a, b0, acc);
    if constexpr (VM >= 0)
        asm volatile("s_waitcnt vmcnt(%0)" :: "i"(VM) : "memory");
    __builtin_amdgcn_s_barrier();
}

template<int LDB>
__device__ __forceinline__ void gemm_mainloop(const char* Ag, const char* Bg,
    char* smem, int KT, int tid, int arow_b, int brow_b, int k0, f32x4 (&acc)[8][4])
{
    // prologue: A0(0),B0(0),A1(0),B1(0),A0(1),B0(1)
    stage_region<LDB, true >(Ag,       smem,          0, tid);
    stage_region<LDB, false>(Bg,       smem + 65536,  0, tid);
    stage_region<LDB, true >(Ag,       smem,          1, tid);
    stage_region<LDB, false>(Bg,       smem + 65536,  1, tid);
    stage_region<LDB, true >(Ag + 128, smem + 32768,  0, tid);
    stage_region<LDB, false>(Bg + 128, smem + 98304,  0, tid);
    asm volatile("s_waitcnt vmcnt(4)" ::: "memory");
    __builtin_amdgcn_s_barrier();

    int cur = 0;
    for (int kt = 0; kt < KT - 2; ++kt) {
        char* Acur = smem + (cur << 15);
        char* Anxt = smem + ((cur ^ 1) << 15);
        char* Bcur = smem + 65536 + (cur << 15);
        char* Bnxt = smem + 65536 + ((cur ^ 1) << 15);
        gwindow<LDB, true, true, 4>(Ag + (size_t)kt * 128, Bg + (size_t)kt * 128,
            Acur, Bcur, Anxt, Bnxt, arow_b, brow_b, k0, tid, acc);
        cur ^= 1;
    }
    {   // window KT-2: stage A1/B1(KT-1) only; drain
        char* Acur = smem + (cur << 15);
        char* Anxt = smem + ((cur ^ 1) << 15);
        char* Bcur = smem + 65536 + (cur << 15);
        char* Bnxt = smem + 65536 + ((cur ^ 1) << 15);
        gwindow<LDB, true, false, 0>(Ag + (size_t)(KT - 2) * 128, Bg + (size_t)(KT - 2) * 128,
            Acur, Bcur, Anxt, Bnxt, arow_b, brow_b, k0, tid, acc);
        cur ^= 1;
    }
    {   // window KT-1: no stages, no wait
        char* Acur = smem + (cur << 15);
        char* Anxt = smem + ((cur ^ 1) << 15);
        char* Bcur = smem + 65536 + (cur << 15);
        char* Bnxt = smem + 65536 + ((cur ^ 1) << 15);
        gwindow<LDB, false, false, -1>(Ag + (size_t)(KT - 1) * 128, Bg + (size_t)(KT - 1) * 128,
            Acur, Bcur, Anxt, Bnxt, arow_b, brow_b, k0, tid, acc);
    }
}

// ---------------------------------------------------------------------------
// Kernel 1: G = gelu(Xb @ W1[e] + b1[e]) -> bf16
// 1D grid, XCD-aware: xcd = L&7; per-XCD: 4 sorted (same-expert) sentences,
// nt fastest (A-panel L2-resident; one expert's B-panels cycle in L2).
// ---------------------------------------------------------------------------
__global__ __launch_bounds__(512, 2) void moe_gemm1(
    const unsigned short* __restrict__ Xb,
    const int*   __restrict__ labels,
    const int*   __restrict__ perm,
    const unsigned short* __restrict__ W1T,  // [E][FFN][HID]
    const float* __restrict__ B1,
    unsigned short* __restrict__ G)
{
    extern __shared__ char smem[];
    const int L = blockIdx.x;
    const int xcd = L & 7, s = L >> 3;       // s in [0,96)
    const int bs = perm[xcd * 4 + s / 24];
    const int rr = s % 24;
    const int mt = rr / 12, nt = rr % 12;
    const int e  = labels[bs];

    const char* Ag = (const char*)(Xb + ((size_t)bs * SEQ + (size_t)mt * 256) * HID);
    const char* Bg = (const char*)(W1T + (size_t)e * FFN * HID + (size_t)nt * 256 * HID);

    const int tid = threadIdx.x;
    const int lane = tid & 63, w = tid >> 6;
    const int wm = (w >> 2) * 128, wn = (w & 3) * 64;
    const int fr = lane & 15, fq = lane >> 4;
    const int arow_b = (wm + fr) * 128, brow_b = (wn + fr) * 128;
    const int k0 = (fq * 16) ^ ((fr & 7) << 4);

    f32x4 acc[8][4];
#pragma unroll
    for (int i = 0; i < 8; i++)
#pragma unroll
        for (int j = 0; j < 4; j++) acc[i][j] = (f32x4)0.0f;

    gemm_mainloop<HID * 2>(Ag, Bg, smem, HID / 64, tid, arow_b, brow_b, k0, acc);

    const float* b1g = B1 + (size_t)e * FFN + (size_t)nt * 256;
    unsigned short* Cg = G + ((size_t)bs * SEQ + (size_t)mt * 256) * FFN + (size_t)nt * 256;
    float bias[4];
#pragma unroll
    for (int nj = 0; nj < 4; nj++) bias[nj] = b1g[wn + nj * 16 + fr];
#pragma unroll
    for (int mi = 0; mi < 8; mi++)
#pragma unroll
        for (int nj = 0; nj < 4; nj++) {
            const int col = wn + nj * 16 + fr;
#pragma unroll
            for (int r = 0; r < 4; r++) {
                const int row = wm + mi * 16 + fq * 4 + r;
                float v = acc[mi][nj][r] + bias[nj];
                Cg[(size_t)row * FFN + col] = f2bf(gelu_fast(v));
            }
        }
}

// ---------------------------------------------------------------------------
// Kernel 2: Out = G @ W2[e] + b2[e] -> fp32
// ---------------------------------------------------------------------------
__global__ __launch_bounds__(512, 2) void moe_gemm2(
    const unsigned short* __restrict__ G,
    const int*   __restrict__ labels,
    const int*   __restrict__ perm,
    const unsigned short* __restrict__ W2T,  // [E][HID][FFN]
    const float* __restrict__ B2,
    float* __restrict__ Out)
{
    extern __shared__ char smem[];
    const int L = blockIdx.x;
    const int xcd = L & 7, s = L >> 3;       // s in [0,24)
    const int bs = perm[xcd * 4 + s / 6];
    const int rr = s % 6;
    const int mt = rr / 3, nt = rr % 3;
    const int e  = labels[bs];

    const char* Ag = (const char*)(G + ((size_t)bs * SEQ + (size_t)mt * 256) * FFN);
    const char* Bg = (const char*)(W2T + (size_t)e * HID * FFN + (size_t)nt * 256 * FFN);

    const int tid = threadIdx.x;
    const int lane = tid & 63, w = tid >> 6;
    const int wm = (w >> 2) * 128, wn = (w & 3) * 64;
    const int fr = lane & 15, fq = lane >> 4;
    const int arow_b = (wm + fr) * 128, brow_b = (wn + fr) * 128;
    const int k0 = (fq * 16) ^ ((fr & 7) << 4);

    f32x4 acc[8][4];
#pragma unroll
    for (int i = 0; i < 8; i++)
#pragma unroll
        for (int j = 0; j < 4; j++) acc[i][j] = (f32x4)0.0f;

    gemm_mainloop<FFN * 2>(Ag, Bg, smem, FFN / 64, tid, arow_b, brow_b, k0, acc);

    const float* b2g = B2 + (size_t)e * HID + (size_t)nt * 256;
    float* Cg = Out + ((size_t)bs * SEQ + (size_t)mt * 256) * HID + (size_t)nt * 256;
    float bias[4];
#pragma unroll
    for (int nj = 0; nj < 4; nj++) bias[nj] = b2g[wn + nj * 16 + fr];
#pragma unroll
    for (int mi = 0; mi < 8; mi++)
#pragma unroll
        for (int nj = 0; nj < 4; nj++) {
            const int col = wn + nj * 16 + fr;
#pragma unroll
            for (int r = 0; r < 4; r++) {
                const int row = wm + mi * 16 + fq * 4 + r;
                Cg[(size_t)row * HID + col] = acc[mi][nj][r] + bias[nj];
            }
        }
}

extern "C" void kernel_launch(void* const* d_in, const int* in_sizes, int n_in,
                              void* d_out, int out_size, void* d_ws, size_t ws_size,
                              hipStream_t stream) {
    const float* X      = (const float*)d_in[0];
    const int*   labels = (const int*)  d_in[1];
    const float* W1     = (const float*)d_in[2];
    const float* B1     = (const float*)d_in[3];
    const float* W2     = (const float*)d_in[4];
    const float* B2     = (const float*)d_in[5];
    float* Out = (float*)d_out;

    char* ws = (char*)d_ws;
    unsigned short* Xb  = (unsigned short*)(ws);               // 25,165,824 B
    unsigned short* W1T = (unsigned short*)(ws + 25165824);    // 37,748,736 B
    unsigned short* W2T = (unsigned short*)(ws + 62914560);    // 37,748,736 B
    unsigned short* G   = (unsigned short*)(ws + 100663296);   // 100,663,296 B
    int*            perm = (int*)(ws + 201326592);             // 128 B

    (void)hipFuncSetAttribute((const void*)moe_gemm1,
        hipFuncAttributeMaxDynamicSharedMemorySize, 131072);
    (void)hipFuncSetAttribute((const void*)moe_gemm2,
        hipFuncAttributeMaxDynamicSharedMemorySize, 131072);

    sort_labels_kernel<<<1, 64, 0, stream>>>(labels, perm);
    cvt_x_kernel<<<2048, 256, 0, stream>>>(X, Xb, NB * SEQ * HID / 8);
    cvt_transpose_kernel<<<dim3(FFN / 64, HID / 64, NEXP), 256, 0, stream>>>(W1, W1T, HID, FFN);
    cvt_transpose_kernel<<<dim3(HID / 64, FFN / 64, NEXP), 256, 0, stream>>>(W2, W2T, FFN, HID);

    moe_gemm1<<<768, dim3(512), 131072, stream>>>(Xb, labels, perm, W1T, B1, G);
    moe_gemm2<<<192, dim3(512), 131072, stream>>>(G, labels, perm, W2T, B2, Out);
}